// Round 7
// baseline (2459.329 us; speedup 1.0000x reference)
//
#include <hip/hip_runtime.h>
#include <hip/hip_bf16.h>

// RNNClassifier: B=64, T=2048, V=50000, E=256, H=256, O=16
// K0: W_ih/W_hh fp32 -> fp16 once into d_ws.
// K1 (MFMA f16): xh16[B*T][H] = fp16( emb[x] @ W_ih^T + b_ih + b_hh ).
// K2 (MFMA f16): scan, 32 WGs x 2 chains x 4 waves, chains software-pipelined
//   in ANTI-PHASE: each slot = chainX.phase1(MFMA) + chainY.phase2(tanh),
//   one lgkmcnt-only barrier per slot. Latencies of the two phases overlap
//   (independent chains) -> attacks the R4-R6 ~1750cyc/step serial floor.

#define B_  64
#define T_  2048
#define E_  256
#define H_  256
#define O_  16
#define H2_ 128

typedef _Float16 f16x4 __attribute__((ext_vector_type(4)));
typedef _Float16 f16x8 __attribute__((ext_vector_type(8)));
typedef float    f32x4 __attribute__((ext_vector_type(4)));

// Barrier without __syncthreads()'s vmcnt(0) drain. Safe: in-loop cross-wave
// communication is LDS-only.
#define LDS_BARRIER() asm volatile("s_waitcnt lgkmcnt(0)\n\ts_barrier" ::: "memory")

__device__ __forceinline__ float tanh_fast(float x) {
  const float e = __expf(2.0f * x);
  return fmaf(-2.0f, __builtin_amdgcn_rcpf(e + 1.0f), 1.0f);
}

// ---------------------------------------------------------------------------
__global__ __launch_bounds__(256) void k0_cvt(
    const float* __restrict__ W_ih, const float* __restrict__ W_hh,
    _Float16* __restrict__ Wih16, _Float16* __restrict__ Whh16) {
  const int i = (blockIdx.x * 256 + threadIdx.x) * 4;
  if (i < H_ * E_) {
    float4 a = *(const float4*)&W_ih[i];
    float4 b = *(const float4*)&W_hh[i];
    f16x4 ah, bh;
    ah[0]=(_Float16)a.x; ah[1]=(_Float16)a.y; ah[2]=(_Float16)a.z; ah[3]=(_Float16)a.w;
    bh[0]=(_Float16)b.x; bh[1]=(_Float16)b.y; bh[2]=(_Float16)b.z; bh[3]=(_Float16)b.w;
    *(f16x4*)&Wih16[i] = ah;
    *(f16x4*)&Whh16[i] = bh;
  }
}

// ---------------------------------------------------------------------------
// K1: gathered GEMM via MFMA (unchanged from R6).
// ---------------------------------------------------------------------------
__global__ __launch_bounds__(256) void k1_xh(
    const int* __restrict__ x, const float* __restrict__ emb,
    const _Float16* __restrict__ Wih16, const float* __restrict__ b_ih,
    const float* __restrict__ b_hh, _Float16* __restrict__ xh) {
  __shared__ _Float16 A16[64][264];
  const int tid  = threadIdx.x;
  const int w    = tid >> 6;
  const int lane = tid & 63;
  const int nl   = lane & 15;
  const int koff = (lane >> 4) << 3;
  const long r0  = (long)blockIdx.x * 64;

  {
    const int c4 = lane << 2;
#pragma unroll
    for (int it = 0; it < 16; ++it) {
      const int row = (it << 2) + w;
      const long tok = x[r0 + row];
      const float4 v = *(const float4*)&emb[tok * E_ + c4];
      f16x4 hv;
      hv[0] = (_Float16)v.x; hv[1] = (_Float16)v.y;
      hv[2] = (_Float16)v.z; hv[3] = (_Float16)v.w;
      *(f16x4*)&A16[row][c4] = hv;
    }
  }

  f16x8 bfr[4][8];
#pragma unroll
  for (int nt = 0; nt < 4; ++nt) {
    const int n = (w << 6) + (nt << 4) + nl;
#pragma unroll
    for (int kt = 0; kt < 8; ++kt)
      bfr[nt][kt] = *(const f16x8*)&Wih16[n * E_ + (kt << 5) + koff];
  }
  __syncthreads();

  f32x4 acc[4][4];
#pragma unroll
  for (int mt = 0; mt < 4; ++mt)
#pragma unroll
    for (int nt = 0; nt < 4; ++nt) acc[mt][nt] = (f32x4){};

#pragma unroll
  for (int mt = 0; mt < 4; ++mt) {
#pragma unroll
    for (int kt = 0; kt < 8; ++kt) {
      const f16x8 a = *(const f16x8*)&A16[(mt << 4) + nl][(kt << 5) + koff];
#pragma unroll
      for (int nt = 0; nt < 4; ++nt)
        acc[mt][nt] = __builtin_amdgcn_mfma_f32_16x16x32_f16(a, bfr[nt][kt], acc[mt][nt], 0, 0, 0);
    }
  }
  __syncthreads();

  {
    const int rsub = (lane >> 4) << 2;
#pragma unroll
    for (int nt = 0; nt < 4; ++nt) {
      const int n = (w << 6) + (nt << 4) + nl;
      const float bias = b_ih[n] + b_hh[n];
#pragma unroll
      for (int mt = 0; mt < 4; ++mt)
#pragma unroll
        for (int j = 0; j < 4; ++j)
          A16[(mt << 4) + rsub + j][n] = (_Float16)(acc[mt][nt][j] + bias);
    }
  }
  __syncthreads();

  {
#pragma unroll
    for (int i = 0; i < 8; ++i) {
      const int row = (w << 4) + (i << 1) + (lane >> 5);
      const int col = (lane & 31) << 3;
      *(f16x8*)&xh[(r0 + row) * H_ + col] = *(const f16x8*)&A16[row][col];
    }
  }
}

// ---------------------------------------------------------------------------
// K2: anti-phase 2-chain scan. Grid = 32 WGs x 256 thr (4 waves).
// Wave w owns W_hh rows [64w, 64w+64) (afr, 128 VGPR). Phase1: MFMA matvec,
// C col 0 -> sc (f32). Phase2: all 256 thr, 1 tanh each -> h16 (fp16).
// ---------------------------------------------------------------------------
__global__ __launch_bounds__(256, 1) void k2_rnn(
    const _Float16* __restrict__ xh, const _Float16* __restrict__ Whh16,
    const float* __restrict__ fc1_w, const float* __restrict__ fc1_b,
    const float* __restrict__ fc2_w, const float* __restrict__ fc2_b,
    float* __restrict__ out) {
  __shared__ _Float16 hA[H_], hB[H_];
  __shared__ float    scA[H_], scB[H_];
  __shared__ float    hid_s[2][H2_ + 4];

  const int tid  = threadIdx.x;
  const int w    = tid >> 6;
  const int lane = tid & 63;
  const int nl   = lane & 15;
  const int quad = lane >> 4;
  const int koff = quad << 3;
  const int cA   = blockIdx.x * 2;

  // A-frags: W_hh rows 64w+16mt+nl, k-chunk quad*8 of tile kt (128 VGPR)
  f16x8 afr[4][8];
#pragma unroll
  for (int mt = 0; mt < 4; ++mt) {
    const int i = (w << 6) + (mt << 4) + nl;
#pragma unroll
    for (int kt = 0; kt < 8; ++kt)
      afr[mt][kt] = *(const f16x8*)&Whh16[i * H_ + (kt << 5) + koff];
  }

  // h0 = 0
  if (tid < 32)      *(f16x8*)&hA[tid << 3] = (f16x8){};
  else if (tid < 64) *(f16x8*)&hB[(tid - 32) << 3] = (f16x8){};

  // xh per-thread streams (element tid of each step), chunk-relay queues
  const _Float16* xA = xh + (size_t)cA * T_ * H_ + tid;
  const _Float16* xB = xA + (size_t)T_ * H_;
  _Float16 qA[4], qB[4], nA[4], nB[4];
#pragma unroll
  for (int s = 0; s < 4; ++s) { qA[s] = xA[(size_t)s * H_];       qB[s] = xB[(size_t)s * H_]; }
#pragma unroll
  for (int s = 0; s < 4; ++s) { nA[s] = xA[(size_t)(4 + s) * H_]; nB[s] = xB[(size_t)(4 + s) * H_]; }
  __syncthreads();

  // SLOT: phase1 on (H1->SC1), phase2 on (SC2 + XV -> H2), one barrier.
#define SLOT(H1, SC1, SC2, XV, H2)                                             \
  {                                                                            \
    const float sv = SC2[tid];            /* issue early, overlaps MFMA */     \
    f16x8 bfr[8];                                                              \
    _Pragma("unroll")                                                          \
    for (int kt = 0; kt < 8; ++kt)                                             \
      bfr[kt] = *(const f16x8*)&H1[(kt << 5) + koff]; /* 16-lane broadcast */  \
    const f32x4 zz = {};                                                       \
    _Pragma("unroll")                                                          \
    for (int mt = 0; mt < 4; ++mt) {                                           \
      f32x4 alo = __builtin_amdgcn_mfma_f32_16x16x32_f16(afr[mt][0], bfr[0], zz, 0, 0, 0);  \
      alo       = __builtin_amdgcn_mfma_f32_16x16x32_f16(afr[mt][1], bfr[1], alo, 0, 0, 0); \
      alo       = __builtin_amdgcn_mfma_f32_16x16x32_f16(afr[mt][2], bfr[2], alo, 0, 0, 0); \
      alo       = __builtin_amdgcn_mfma_f32_16x16x32_f16(afr[mt][3], bfr[3], alo, 0, 0, 0); \
      f32x4 ahi = __builtin_amdgcn_mfma_f32_16x16x32_f16(afr[mt][4], bfr[4], zz, 0, 0, 0);  \
      ahi       = __builtin_amdgcn_mfma_f32_16x16x32_f16(afr[mt][5], bfr[5], ahi, 0, 0, 0); \
      ahi       = __builtin_amdgcn_mfma_f32_16x16x32_f16(afr[mt][6], bfr[6], ahi, 0, 0, 0); \
      ahi       = __builtin_amdgcn_mfma_f32_16x16x32_f16(afr[mt][7], bfr[7], ahi, 0, 0, 0); \
      const f32x4 sum = alo + ahi;                                             \
      if (nl == 0)                                                             \
        *(f32x4*)&SC1[(w << 6) + (mt << 4) + (quad << 2)] = sum;               \
    }                                                                          \
    H2[tid] = (_Float16)tanh_fast(sv + (float)(XV));                           \
    LDS_BARRIER();                                                             \
  }

  // Phase1-only prologue slot: A.ph1(0)
  {
    f16x8 bfr[8];
#pragma unroll
    for (int kt = 0; kt < 8; ++kt)
      bfr[kt] = *(const f16x8*)&hA[(kt << 5) + koff];
    const f32x4 zz = {};
#pragma unroll
    for (int mt = 0; mt < 4; ++mt) {
      f32x4 alo = __builtin_amdgcn_mfma_f32_16x16x32_f16(afr[mt][0], bfr[0], zz, 0, 0, 0);
      alo       = __builtin_amdgcn_mfma_f32_16x16x32_f16(afr[mt][1], bfr[1], alo, 0, 0, 0);
      alo       = __builtin_amdgcn_mfma_f32_16x16x32_f16(afr[mt][2], bfr[2], alo, 0, 0, 0);
      alo       = __builtin_amdgcn_mfma_f32_16x16x32_f16(afr[mt][3], bfr[3], alo, 0, 0, 0);
      f32x4 ahi = __builtin_amdgcn_mfma_f32_16x16x32_f16(afr[mt][4], bfr[4], zz, 0, 0, 0);
      ahi       = __builtin_amdgcn_mfma_f32_16x16x32_f16(afr[mt][5], bfr[5], ahi, 0, 0, 0);
      ahi       = __builtin_amdgcn_mfma_f32_16x16x32_f16(afr[mt][6], bfr[6], ahi, 0, 0, 0);
      ahi       = __builtin_amdgcn_mfma_f32_16x16x32_f16(afr[mt][7], bfr[7], ahi, 0, 0, 0);
      const f32x4 sum = alo + ahi;
      if (nl == 0)
        *(f32x4*)&scA[(w << 6) + (mt << 4) + (quad << 2)] = sum;
    }
    LDS_BARRIER();
  }

  // Main: blocks of 4 steps; last block peeled for the tail.
  for (int tt = 0; tt < T_ - 4; tt += 4) {
#pragma unroll
    for (int u = 0; u < 4; ++u) {
      SLOT(hB, scB, scA, qA[u], hA)   // B.ph1(t), A.ph2(t)
      SLOT(hA, scA, scB, qB[u], hB)   // A.ph1(t+1), B.ph2(t)
    }
    // relay rotate: waits on loads issued one full block (8 slots) earlier
#pragma unroll
    for (int s = 0; s < 4; ++s) { qA[s] = nA[s]; qB[s] = nB[s]; }
    const int tn = tt + 8;
#pragma unroll
    for (int s = 0; s < 4; ++s) {
      const size_t ti = (size_t)((tn + s) & (T_ - 1)) * H_;  // clamp; tail unused
      nA[s] = xA[ti]; nB[s] = xB[ti];
    }
  }
  // tail block: t = 2044..2047
#pragma unroll
  for (int u = 0; u < 3; ++u) {
    SLOT(hB, scB, scA, qA[u], hA)
    SLOT(hA, scA, scB, qB[u], hB)
  }
  SLOT(hB, scB, scA, qA[3], hA)       // B.ph1(2047), A.ph2(2047)
  {                                    // B.ph2(2047)
    const float sv = scB[tid];
    hB[tid] = (_Float16)tanh_fast(sv + (float)qB[3]);
  }
#undef SLOT

  __syncthreads();  // full drain before epilogue

  // MLP head for 2 chains: thread -> chain tid>>7, output o = tid&127
  {
    const int c = tid >> 7, o = tid & 127;
    const _Float16* hf = c ? hB : hA;
    float s = fc1_b[o];
#pragma unroll 8
    for (int k = 0; k < H_; ++k) s += fc1_w[o * H_ + k] * (float)hf[k];
    hid_s[c][o] = fmaxf(s, 0.f);
  }
  __syncthreads();
  if (tid < 2 * O_) {
    const int c = tid >> 4, o = tid & 15;
    float s = fc2_b[o];
#pragma unroll 8
    for (int k = 0; k < H2_; ++k) s += fc2_w[o * H2_ + k] * hid_s[c][k];
    out[(size_t)(cA + c) * O_ + o] = s;
  }
}

extern "C" void kernel_launch(void* const* d_in, const int* in_sizes, int n_in,
                              void* d_out, int out_size, void* d_ws, size_t ws_size,
                              hipStream_t stream) {
  const int*   x     = (const int*)d_in[0];
  const float* emb   = (const float*)d_in[1];
  const float* W_ih  = (const float*)d_in[2];
  const float* W_hh  = (const float*)d_in[3];
  const float* b_ih  = (const float*)d_in[4];
  const float* b_hh  = (const float*)d_in[5];
  const float* fc1_w = (const float*)d_in[6];
  const float* fc1_b = (const float*)d_in[7];
  const float* fc2_w = (const float*)d_in[8];
  const float* fc2_b = (const float*)d_in[9];
  float* outp = (float*)d_out;

  _Float16* xh16  = (_Float16*)d_ws;                    // 64 MiB
  _Float16* Wih16 = xh16 + (size_t)B_ * T_ * H_;        // 128 KiB
  _Float16* Whh16 = Wih16 + (size_t)H_ * E_;            // 128 KiB

  k0_cvt<<<dim3(H_ * E_ / 1024), dim3(256), 0, stream>>>(W_ih, W_hh, Wih16, Whh16);
  k1_xh<<<dim3(B_ * T_ / 64), dim3(256), 0, stream>>>(x, emb, Wih16, b_ih, b_hh, xh16);
  k2_rnn<<<dim3(B_ / 2), dim3(256), 0, stream>>>(xh16, Whh16, fc1_w, fc1_b, fc2_w, fc2_b, outp);
}

// Round 8
// 2270.072 us; speedup vs baseline: 1.0834x; 1.0834x over previous
//
#include <hip/hip_runtime.h>
#include <hip/hip_bf16.h>

// RNNClassifier: B=64, T=2048, V=50000, E=256, H=256, O=16
// K0: W_ih/W_hh fp32 -> fp16 once into d_ws.
// K1 (MFMA f16): xh16[B*T][H] = fp16( emb[x] @ W_ih^T + b_ih + b_hh ).
// K2 (MFMA f16): scan. 4 WGs x 16 chains x 8 waves (2 waves/SIMD).
//   Wave w owns M rows [32w,32w+32): 16 MFMA/step, ALL 16 B-columns used
//   (full MFMA efficiency; per-SIMD mfma pipe = 2 waves x 258 = 516 cyc/step
//   = the hard floor for one 16-chain group per CU). 2 waves/SIMD hide the
//   serial tail (tanh/LDS/barrier) under the mate's MFMA issue.
//   1 lgkm-only barrier/step; chunk-relay xh prefetch (no in-loop vmcnt);
//   h ping-pongs in LDS [chunk][chain] (bank-minimal both directions).

#define B_  64
#define T_  2048
#define E_  256
#define H_  256
#define O_  16
#define H2_ 128

typedef _Float16 f16x4 __attribute__((ext_vector_type(4)));
typedef _Float16 f16x8 __attribute__((ext_vector_type(8)));
typedef float    f32x4 __attribute__((ext_vector_type(4)));

// Barrier without __syncthreads()'s vmcnt(0) drain. Safe: in-loop cross-wave
// communication is LDS-only.
#define LDS_BARRIER() asm volatile("s_waitcnt lgkmcnt(0)\n\ts_barrier" ::: "memory")

__device__ __forceinline__ float tanh_fast(float x) {
  const float e = __expf(2.0f * x);
  return fmaf(-2.0f, __builtin_amdgcn_rcpf(e + 1.0f), 1.0f);
}

// ---------------------------------------------------------------------------
__global__ __launch_bounds__(256) void k0_cvt(
    const float* __restrict__ W_ih, const float* __restrict__ W_hh,
    _Float16* __restrict__ Wih16, _Float16* __restrict__ Whh16) {
  const int i = (blockIdx.x * 256 + threadIdx.x) * 4;
  if (i < H_ * E_) {
    float4 a = *(const float4*)&W_ih[i];
    float4 b = *(const float4*)&W_hh[i];
    f16x4 ah, bh;
    ah[0]=(_Float16)a.x; ah[1]=(_Float16)a.y; ah[2]=(_Float16)a.z; ah[3]=(_Float16)a.w;
    bh[0]=(_Float16)b.x; bh[1]=(_Float16)b.y; bh[2]=(_Float16)b.z; bh[3]=(_Float16)b.w;
    *(f16x4*)&Wih16[i] = ah;
    *(f16x4*)&Whh16[i] = bh;
  }
}

// ---------------------------------------------------------------------------
// K1: gathered GEMM via MFMA (unchanged from R6).
// ---------------------------------------------------------------------------
__global__ __launch_bounds__(256) void k1_xh(
    const int* __restrict__ x, const float* __restrict__ emb,
    const _Float16* __restrict__ Wih16, const float* __restrict__ b_ih,
    const float* __restrict__ b_hh, _Float16* __restrict__ xh) {
  __shared__ _Float16 A16[64][264];
  const int tid  = threadIdx.x;
  const int w    = tid >> 6;
  const int lane = tid & 63;
  const int nl   = lane & 15;
  const int koff = (lane >> 4) << 3;
  const long r0  = (long)blockIdx.x * 64;

  {
    const int c4 = lane << 2;
#pragma unroll
    for (int it = 0; it < 16; ++it) {
      const int row = (it << 2) + w;
      const long tok = x[r0 + row];
      const float4 v = *(const float4*)&emb[tok * E_ + c4];
      f16x4 hv;
      hv[0] = (_Float16)v.x; hv[1] = (_Float16)v.y;
      hv[2] = (_Float16)v.z; hv[3] = (_Float16)v.w;
      *(f16x4*)&A16[row][c4] = hv;
    }
  }

  f16x8 bfr[4][8];
#pragma unroll
  for (int nt = 0; nt < 4; ++nt) {
    const int n = (w << 6) + (nt << 4) + nl;
#pragma unroll
    for (int kt = 0; kt < 8; ++kt)
      bfr[nt][kt] = *(const f16x8*)&Wih16[n * E_ + (kt << 5) + koff];
  }
  __syncthreads();

  f32x4 acc[4][4];
#pragma unroll
  for (int mt = 0; mt < 4; ++mt)
#pragma unroll
    for (int nt = 0; nt < 4; ++nt) acc[mt][nt] = (f32x4){};

#pragma unroll
  for (int mt = 0; mt < 4; ++mt) {
#pragma unroll
    for (int kt = 0; kt < 8; ++kt) {
      const f16x8 a = *(const f16x8*)&A16[(mt << 4) + nl][(kt << 5) + koff];
#pragma unroll
      for (int nt = 0; nt < 4; ++nt)
        acc[mt][nt] = __builtin_amdgcn_mfma_f32_16x16x32_f16(a, bfr[nt][kt], acc[mt][nt], 0, 0, 0);
    }
  }
  __syncthreads();

  {
    const int rsub = (lane >> 4) << 2;
#pragma unroll
    for (int nt = 0; nt < 4; ++nt) {
      const int n = (w << 6) + (nt << 4) + nl;
      const float bias = b_ih[n] + b_hh[n];
#pragma unroll
      for (int mt = 0; mt < 4; ++mt)
#pragma unroll
        for (int j = 0; j < 4; ++j)
          A16[(mt << 4) + rsub + j][n] = (_Float16)(acc[mt][nt][j] + bias);
    }
  }
  __syncthreads();

  {
#pragma unroll
    for (int i = 0; i < 8; ++i) {
      const int row = (w << 4) + (i << 1) + (lane >> 5);
      const int col = (lane & 31) << 3;
      *(f16x8*)&xh[(r0 + row) * H_ + col] = *(const f16x8*)&A16[row][col];
    }
  }
}

// ---------------------------------------------------------------------------
// K2: 16-chain scan, 8 waves (2/SIMD). h LDS layout: hb[buf][chunk][chain][8]
// where chunk = k/8 (32 chunks). B-frag read: lane(q,nl) kt -> chunk kt*4+q,
// chain nl (16B aligned, bank-minimal). Write: lane(q,nl) mt -> rows
// 32w+16mt+4q+r -> chunk 4w+2mt+(q>>1), offset (q&1)*4.
// ---------------------------------------------------------------------------
__global__ __launch_bounds__(512, 2) void k2_rnn(
    const _Float16* __restrict__ xh, const _Float16* __restrict__ Whh16,
    const float* __restrict__ fc1_w, const float* __restrict__ fc1_b,
    const float* __restrict__ fc2_w, const float* __restrict__ fc2_b,
    float* __restrict__ out) {
  __shared__ _Float16 hb[2][32][16][8];     // 2 x 8KB ping-pong
  __shared__ float    hid_s[16][H2_ + 4];

  const int tid  = threadIdx.x;
  const int w    = tid >> 6;                // wave 0..7: M rows [32w,32w+32)
  const int lane = tid & 63;
  const int nl   = lane & 15;               // chain / A-row-low
  const int quad = lane >> 4;
  const int koff = quad << 3;
  const int c0   = blockIdx.x * 16;

  // A-frags: W_hh rows 32w+16mt+nl (fp16), 64 VGPRs
  f16x8 afr[2][8];
#pragma unroll
  for (int mt = 0; mt < 2; ++mt) {
    const int i = (w << 5) + (mt << 4) + nl;
#pragma unroll
    for (int kt = 0; kt < 8; ++kt)
      afr[mt][kt] = *(const f16x8*)&Whh16[i * H_ + (kt << 5) + koff];
  }

  // h0 = 0: 4096 halves, 512 thr x 8
  *(f16x8*)&(((_Float16*)hb[0])[tid << 3]) = (f16x8){};

  // xh stream: chain c0+nl, rows 32w+16mt+4q (+r), t-major
  const _Float16* xb = xh + (size_t)(c0 + nl) * (T_ * H_) + (w << 5) + (quad << 2);

  // chunk-relay: q = steps tt..tt+3, n = steps tt+4..tt+7
  f16x4 xq[4][2], xn[4][2];
#pragma unroll
  for (int s = 0; s < 4; ++s)
#pragma unroll
    for (int mt = 0; mt < 2; ++mt) {
      xq[s][mt] = *(const f16x4*)&xb[(size_t)s * H_ + (mt << 4)];
      xn[s][mt] = *(const f16x4*)&xb[(size_t)(4 + s) * H_ + (mt << 4)];
    }
  __syncthreads();

#define STEP(RB, WB, U)                                                        \
  {                                                                            \
    f16x8 bfr[8];                                                              \
    _Pragma("unroll")                                                          \
    for (int kt = 0; kt < 8; ++kt)                                             \
      bfr[kt] = *(const f16x8*)&hb[RB][(kt << 2) + quad][nl][0];               \
    const f32x4 zz = {};                                                       \
    _Pragma("unroll")                                                          \
    for (int mt = 0; mt < 2; ++mt) {                                           \
      f32x4 xc;                                                                \
      _Pragma("unroll")                                                        \
      for (int j = 0; j < 4; ++j) xc[j] = (float)xq[U][mt][j];                 \
      f32x4 alo = __builtin_amdgcn_mfma_f32_16x16x32_f16(afr[mt][0], bfr[0], xc, 0, 0, 0); \
      alo       = __builtin_amdgcn_mfma_f32_16x16x32_f16(afr[mt][1], bfr[1], alo, 0, 0, 0); \
      alo       = __builtin_amdgcn_mfma_f32_16x16x32_f16(afr[mt][2], bfr[2], alo, 0, 0, 0); \
      alo       = __builtin_amdgcn_mfma_f32_16x16x32_f16(afr[mt][3], bfr[3], alo, 0, 0, 0); \
      f32x4 ahi = __builtin_amdgcn_mfma_f32_16x16x32_f16(afr[mt][4], bfr[4], zz, 0, 0, 0);  \
      ahi       = __builtin_amdgcn_mfma_f32_16x16x32_f16(afr[mt][5], bfr[5], ahi, 0, 0, 0); \
      ahi       = __builtin_amdgcn_mfma_f32_16x16x32_f16(afr[mt][6], bfr[6], ahi, 0, 0, 0); \
      ahi       = __builtin_amdgcn_mfma_f32_16x16x32_f16(afr[mt][7], bfr[7], ahi, 0, 0, 0); \
      const f32x4 sm = alo + ahi;                                              \
      f16x4 o;                                                                 \
      _Pragma("unroll")                                                        \
      for (int j = 0; j < 4; ++j) o[j] = (_Float16)tanh_fast(sm[j]);           \
      *(f16x4*)&hb[WB][(w << 2) + (mt << 1) + (quad >> 1)][nl][(quad & 1) << 2] = o; \
    }                                                                          \
    LDS_BARRIER();                                                             \
  }

  for (int tt = 0; tt < T_; tt += 4) {
    STEP(0, 1, 0)
    STEP(1, 0, 1)
    STEP(0, 1, 2)
    STEP(1, 0, 3)
    // relay rotate: waits here on loads issued a full chunk (4 steps) ago
#pragma unroll
    for (int s = 0; s < 4; ++s)
#pragma unroll
      for (int mt = 0; mt < 2; ++mt) xq[s][mt] = xn[s][mt];
    const int tn = tt + 8;
#pragma unroll
    for (int s = 0; s < 4; ++s) {
      const size_t ti = (size_t)((tn + s) & (T_ - 1)) * H_;  // wrap; tail unused
#pragma unroll
      for (int mt = 0; mt < 2; ++mt)
        xn[s][mt] = *(const f16x4*)&xb[ti + (mt << 4)];
    }
  }
#undef STEP

  __syncthreads();  // full drain before epilogue

  // MLP head; final h in hb[0]. h(c,k) = hb[0][k>>3][c][k&7].
#pragma unroll
  for (int p = 0; p < 4; ++p) {
    const int c = (tid >> 7) + (p << 2);
    const int o = tid & 127;
    float s = fc1_b[o];
#pragma unroll 8
    for (int k = 0; k < H_; ++k) s += fc1_w[o * H_ + k] * (float)hb[0][k >> 3][c][k & 7];
    hid_s[c][o] = fmaxf(s, 0.f);
  }
  __syncthreads();
  if (tid < 16 * O_) {
    const int c = tid >> 4, o = tid & 15;
    float s = fc2_b[o];
#pragma unroll 8
    for (int k = 0; k < H2_; ++k) s += fc2_w[o * H2_ + k] * hid_s[c][k];
    out[(size_t)(c0 + c) * O_ + o] = s;
  }
}

extern "C" void kernel_launch(void* const* d_in, const int* in_sizes, int n_in,
                              void* d_out, int out_size, void* d_ws, size_t ws_size,
                              hipStream_t stream) {
  const int*   x     = (const int*)d_in[0];
  const float* emb   = (const float*)d_in[1];
  const float* W_ih  = (const float*)d_in[2];
  const float* W_hh  = (const float*)d_in[3];
  const float* b_ih  = (const float*)d_in[4];
  const float* b_hh  = (const float*)d_in[5];
  const float* fc1_w = (const float*)d_in[6];
  const float* fc1_b = (const float*)d_in[7];
  const float* fc2_w = (const float*)d_in[8];
  const float* fc2_b = (const float*)d_in[9];
  float* outp = (float*)d_out;

  _Float16* xh16  = (_Float16*)d_ws;                    // 64 MiB
  _Float16* Wih16 = xh16 + (size_t)B_ * T_ * H_;        // 128 KiB
  _Float16* Whh16 = Wih16 + (size_t)H_ * E_;            // 128 KiB

  k0_cvt<<<dim3(H_ * E_ / 1024), dim3(256), 0, stream>>>(W_ih, W_hh, Wih16, Whh16);
  k1_xh<<<dim3(B_ * T_ / 64), dim3(256), 0, stream>>>(x, emb, Wih16, b_ih, b_hh, xh16);
  k2_rnn<<<dim3(B_ / 16), dim3(512), 0, stream>>>(xh16, Whh16, fc1_w, fc1_b, fc2_w, fc2_b, outp);
}